// Round 1
// baseline (73.955 us; speedup 1.0000x reference)
//
#include <hip/hip_runtime.h>
#include <stdint.h>

// Problem constants (fixed by reference setup_inputs)
#define B_     8
#define N_     48
#define M_     (N_ * N_)        // 2304 vectors per batch
#define RPB    16               // rows of the pair matrix per block
#define CHUNKS (M_ / RPB)       // 144
#define NBLK   (B_ * CHUNKS)    // 1152
#define TPB    256

// Kernel 1: each block handles one (batch b, 16-row chunk) of the 2304x2304
// pair matrix. Rebuilds the per-batch vector table (vx, vy, 1/norm) in LDS,
// then sweeps rows with 4x register blocking over columns.
__global__ __launch_bounds__(TPB) void pair_kernel(
    const float* __restrict__ gt,    // [B, N, 2]
    const float* __restrict__ sm,    // [B, N, N]
    const float* __restrict__ thrp,  // [1]
    float* __restrict__ partS,       // [NBLK]
    unsigned int* __restrict__ partC)// [NBLK]
{
    __shared__ float4 tile[M_];      // (vx, vy, w=1/norm, pad) : 36 KB
    __shared__ float  gx[N_], gy[N_];
    __shared__ float  redS[4];
    __shared__ unsigned int redC[4];

    const int tid   = threadIdx.x;
    const int b     = blockIdx.x / CHUNKS;
    const int chunk = blockIdx.x % CHUNKS;

    if (tid < N_) {
        float2 g = ((const float2*)gt)[b * N_ + tid];
        gx[tid] = g.x;
        gy[tid] = g.y;
    }
    __syncthreads();

    const float thr = thrp[0];
    // Build vector table: v = (gt[i] - gt[j]) * sm_thresholded, w = 1/sqrt(|v|^2 + 2e-9)
    for (int idx = tid; idx < M_; idx += TPB) {
        float s = sm[b * M_ + idx];
        s = (s < thr) ? 0.0f : s;
        int i = idx / N_;
        int j = idx - i * N_;
        // exact IEEE single ops; matches numpy's (gt_i - gt_j) * sm
        float vx = __fmul_rn(__fsub_rn(gx[i], gx[j]), s);
        float vy = __fmul_rn(__fsub_rn(gy[i], gy[j]), s);
        // vabs = sqrt(vx^2 + eps + vy^2 + eps); small rounding diffs only scale terms
        float ss = vx * vx + vy * vy + 2e-9f;
        tile[idx] = make_float4(vx, vy, rsqrtf(ss), 0.0f);
    }
    __syncthreads();

    const int m0 = chunk * RPB;
    float total = 0.0f;
    unsigned int cnt = 0;

    #pragma unroll
    for (int g = 0; g < RPB / 4; ++g) {
        const float4 r0 = tile[m0 + g * 4 + 0];   // LDS broadcast (free)
        const float4 r1 = tile[m0 + g * 4 + 1];
        const float4 r2 = tile[m0 + g * 4 + 2];
        const float4 r3 = tile[m0 + g * 4 + 3];
        float a0 = 0.0f, a1 = 0.0f, a2 = 0.0f, a3 = 0.0f;
        for (int n = tid; n < M_; n += TPB) {     // 9 iterations exactly
            const float4 c = tile[n];             // one ds_read_b128, reused x4 rows
            // dot kept as discrete mul/mul/add (no fma contraction) so the
            // exact-zero count matches the fp32 reference semantics
            float d0 = __fadd_rn(__fmul_rn(r0.x, c.x), __fmul_rn(r0.y, c.y));
            float d1 = __fadd_rn(__fmul_rn(r1.x, c.x), __fmul_rn(r1.y, c.y));
            float d2 = __fadd_rn(__fmul_rn(r2.x, c.x), __fmul_rn(r2.y, c.y));
            float d3 = __fadd_rn(__fmul_rn(r3.x, c.x), __fmul_rn(r3.y, c.y));
            cnt += (d0 != 0.0f);
            cnt += (d1 != 0.0f);
            cnt += (d2 != 0.0f);
            cnt += (d3 != 0.0f);
            a0 = fmaf(fabsf(d0), c.z, a0);
            a1 = fmaf(fabsf(d1), c.z, a1);
            a2 = fmaf(fabsf(d2), c.z, a2);
            a3 = fmaf(fabsf(d3), c.z, a3);
        }
        // hoisted row-norm division: multiply row partial by w_m once
        total = fmaf(a0, r0.z, total);
        total = fmaf(a1, r1.z, total);
        total = fmaf(a2, r2.z, total);
        total = fmaf(a3, r3.z, total);
    }

    // wave64 shuffle reduce, then cross-wave via LDS
    for (int off = 32; off > 0; off >>= 1) {
        total += __shfl_down(total, off, 64);
        cnt   += __shfl_down(cnt,   off, 64);
    }
    const int wave = tid >> 6;
    if ((tid & 63) == 0) { redS[wave] = total; redC[wave] = cnt; }
    __syncthreads();
    if (tid == 0) {
        partS[blockIdx.x] = redS[0] + redS[1] + redS[2] + redS[3];
        partC[blockIdx.x] = redC[0] + redC[1] + redC[2] + redC[3];
    }
}

// Kernel 2: reduce the 1152 block partials (double accumulation) and divide.
__global__ __launch_bounds__(256) void finalize_kernel(
    const float* __restrict__ partS,
    const unsigned int* __restrict__ partC,
    float* __restrict__ out)
{
    __shared__ double rs[4];
    __shared__ double rc[4];
    const int tid = threadIdx.x;
    double s = 0.0, c = 0.0;
    for (int i = tid; i < NBLK; i += 256) {
        s += (double)partS[i];
        c += (double)partC[i];
    }
    for (int off = 32; off > 0; off >>= 1) {
        s += __shfl_down(s, off, 64);
        c += __shfl_down(c, off, 64);
    }
    const int wave = tid >> 6;
    if ((tid & 63) == 0) { rs[wave] = s; rc[wave] = c; }
    __syncthreads();
    if (tid == 0) {
        double stot = rs[0] + rs[1] + rs[2] + rs[3];
        double ctot = rc[0] + rc[1] + rc[2] + rc[3];
        out[0] = (float)(stot / ctot);
    }
}

extern "C" void kernel_launch(void* const* d_in, const int* in_sizes, int n_in,
                              void* d_out, int out_size, void* d_ws, size_t ws_size,
                              hipStream_t stream) {
    const float* gt  = (const float*)d_in[0];   // [8,48,2]
    const float* sm  = (const float*)d_in[1];   // [8,48,48]
    const float* thr = (const float*)d_in[2];   // [1]

    float*        partS = (float*)d_ws;
    unsigned int* partC = (unsigned int*)((char*)d_ws + NBLK * sizeof(float));

    pair_kernel<<<NBLK, TPB, 0, stream>>>(gt, sm, thr, partS, partC);
    finalize_kernel<<<1, 256, 0, stream>>>(partS, partC, (float*)d_out);
}